// Round 5
// baseline (377.595 us; speedup 1.0000x reference)
//
#include <hip/hip_runtime.h>
#include <hip/hip_bf16.h>
#include <math.h>

#define B 4
#define L 2048
#define H 8
#define D 64
#define SK 40
#define U 40
#define JC 32          // j-chunks in k_ctx
#define JCL (L / JC)   // 64 j per chunk

// ws layout (bytes)
#define OFF_M    0                  // B*H*L floats = 262144 B
#define OFF_TOP  262144             // B*H*U ints  = 5120 B
#define OFF_T    270336             // B*H*U*L floats = 10485760 B
#define OFF_PART 10756096           // JC * B*H*U*D floats = 10485760 B  (end ~21.2 MB)

__device__ __forceinline__ float dot4(float4 a, float4 b) {
    return fmaf(a.x, b.x, fmaf(a.y, b.y, fmaf(a.z, b.z, a.w * b.w)));
}

// K1: M[b,h,q] = max_s dot(Q[bhq], K[bh,idx[q,s]]) - (1/L) * sum_s dot(...)
// XCD-locality: blockIdx%8 == b*2+hh pins each (b, h-half) to one XCD whose
// K working set is 2.1 MB < 4 MB L2.
__global__ __launch_bounds__(256) void k_msamp(const float* __restrict__ Q,
                                               const float* __restrict__ K,
                                               const int* __restrict__ idx,
                                               float* __restrict__ M) {
    int g  = blockIdx.x & 7;        // = b*2 + hh  (XCD id under %8 round-robin)
    int b  = g >> 1;
    int hh = g & 1;
    int t  = threadIdx.x;
    int q  = (blockIdx.x >> 3) * 4 + (t >> 6);
    int c  = t & 15;                // 16 c-chunks of 4 floats
    int hp = (t >> 4) & 3;          // h' within half
    int h  = hh * 4 + hp;

    float4 q4 = *((const float4*)(Q + (size_t)((b * L + q) * H + h) * D) + c);

    const int* ip = idx + q * SK;   // wave-uniform
    const float* kbase = K + (size_t)b * L * H * D + (size_t)h * D + c * 4;

    float vmax = -__builtin_inff();
    float vsum = 0.f;
#pragma unroll 8
    for (int s = 0; s < SK; ++s) {
        int kidx = ip[s];           // wave-uniform
        float4 k4 = *(const float4*)(kbase + (size_t)kidx * (H * D));
        float d4 = dot4(q4, k4);
        d4 += __shfl_xor(d4, 1, 64);
        d4 += __shfl_xor(d4, 2, 64);
        d4 += __shfl_xor(d4, 4, 64);
        d4 += __shfl_xor(d4, 8, 64);
        vmax = fmaxf(vmax, d4);
        vsum += d4;
    }
    if (c == 0) M[(size_t)(b * H + h) * L + q] = vmax - vsum * (1.0f / (float)L);
}

// K2: top-U per (b,h) via radix-threshold select + exact candidate ranking.
// Order: value descending, ties -> lowest index (== jax.lax.top_k).
__global__ __launch_bounds__(256) void k_topk(const float* __restrict__ M,
                                              int* __restrict__ top) {
    __shared__ unsigned int sv[L];            // sortable keys, 8 KB
    __shared__ unsigned long long cand[L];    // worst-case candidate buffer, 16 KB
    __shared__ unsigned int bins[256];
    __shared__ unsigned int suf[256];
    __shared__ int cnt2;

    int bh = blockIdx.x;
    int tid = threadIdx.x;
    const float* m = M + (size_t)bh * L;

    bins[tid] = 0;
    if (tid == 0) cnt2 = 0;
    __syncthreads();

    // load 8 values/thread, map to sortable uint, histogram top 8 bits
    unsigned int u8[8];
#pragma unroll
    for (int e = 0; e < 8; ++e) {
        int i = tid * 8 + e;
        unsigned int bits = __float_as_uint(m[i]);
        unsigned int u = (bits & 0x80000000u) ? ~bits : (bits | 0x80000000u);
        u8[e] = u;
        sv[i] = u;
        atomicAdd(&bins[u >> 24], 1u);
    }
    __syncthreads();

    // inclusive suffix-sum: suf[i] = #values with top-byte >= i
    suf[tid] = bins[tid];
    __syncthreads();
    for (int s = 1; s < 256; s <<= 1) {
        unsigned int add = (tid + s < 256) ? suf[tid + s] : 0u;
        __syncthreads();
        suf[tid] += add;
        __syncthreads();
    }
    // t = max i with suf[i] >= U; suf is non-increasing -> t = count(suf>=U)-1
    int cnt = __syncthreads_count(suf[tid] >= U);
    unsigned int t = (unsigned int)(cnt - 1);

    // collect candidates: all values with top-byte >= t
#pragma unroll
    for (int e = 0; e < 8; ++e) {
        unsigned int u = u8[e];
        if ((u >> 24) >= t) {
            int pos = atomicAdd(&cnt2, 1);
            int i = tid * 8 + e;
            cand[pos] = ((unsigned long long)u << 11) | (unsigned long long)(2047 - i);
        }
    }
    __syncthreads();
    int C = cnt2;

    // exact rank of each candidate (keys all distinct); write top-U
    for (int j = tid; j < C; j += 256) {
        unsigned long long kj = cand[j];
        int r = 0;
        for (int kk = 0; kk < C; ++kk) r += (cand[kk] > kj);
        if (r < U) top[bh * U + r] = 2047 - (int)(kj & 0x7FFull);
    }
}

// K3a: T[bh,u,k] = 0.125 * dot(Q[bh, top[bh,u]], K[bh,k])
__global__ __launch_bounds__(256) void k_scores(const float* __restrict__ Q,
                                                const float* __restrict__ K,
                                                const int* __restrict__ top,
                                                float* __restrict__ T) {
    __shared__ float4 sQ4[U * 16];   // 40 rows x 64 floats = 10 KB
    int bh = blockIdx.x >> 4;        // 16 k-chunks
    int kc = blockIdx.x & 15;
    int b = bh >> 3, h = bh & (H - 1);
    int tid = threadIdx.x;
    int lane = tid & 63;
    int w = tid >> 6;

    for (int i = tid; i < U * 16; i += 256) {
        int u = i >> 4, c = i & 15;
        int qidx = top[bh * U + u];
        sQ4[i] = *((const float4*)(Q + (size_t)((b * L + qidx) * H + h) * D) + c);
    }

    int k0 = kc * 128 + lane;
    const float4* kr0 = (const float4*)(K + (size_t)((b * L + k0) * H + h) * D);
    const float4* kr1 = (const float4*)(K + (size_t)((b * L + k0 + 64) * H + h) * D);
    float4 kv0[16], kv1[16];
#pragma unroll
    for (int i = 0; i < 16; ++i) { kv0[i] = kr0[i]; kv1[i] = kr1[i]; }
    __syncthreads();

    float* Tb = T + (size_t)bh * U * L;
    for (int uu = 0; uu < 10; ++uu) {
        int u = w * 10 + uu;
        float s0 = 0.f, s1 = 0.f;
#pragma unroll
        for (int i = 0; i < 16; ++i) {
            float4 q4 = sQ4[u * 16 + i];   // broadcast LDS read
            s0 += dot4(q4, kv0[i]);
            s1 += dot4(q4, kv1[i]);
        }
        Tb[(size_t)u * L + k0]      = s0 * 0.125f;
        Tb[(size_t)u * L + k0 + 64] = s1 * 0.125f;
    }
}

// K3b: per row (bh,u): softmax over k then suffix-sum -> T[u,j] = sum_{k>=j} attn[k]
__global__ __launch_bounds__(256) void k_softsuf(float* __restrict__ T) {
    __shared__ float red[256];
    __shared__ float arr[256];
    int row = blockIdx.x;                  // [0, B*H*U)
    float* t = T + (size_t)row * L;
    int tid = threadIdx.x;

    const float4* p = (const float4*)(t + tid * 8);
    float4 a = p[0], c = p[1];
    float x[8] = {a.x, a.y, a.z, a.w, c.x, c.y, c.z, c.w};

    float mx = x[0];
#pragma unroll
    for (int i = 1; i < 8; ++i) mx = fmaxf(mx, x[i]);
    red[tid] = mx;
    __syncthreads();
    for (int s = 128; s; s >>= 1) {
        if (tid < s) red[tid] = fmaxf(red[tid], red[tid + s]);
        __syncthreads();
    }
    float maxv = red[0];
    __syncthreads();

    float e[8];
#pragma unroll
    for (int i = 0; i < 8; ++i) e[i] = __expf(x[i] - maxv);
    float ls[8];
    ls[7] = e[7];
#pragma unroll
    for (int i = 6; i >= 0; --i) ls[i] = e[i] + ls[i + 1];
    float mytotal = ls[0];

    arr[tid] = mytotal;
    __syncthreads();
    for (int s = 1; s < 256; s <<= 1) {
        float add = (tid + s < 256) ? arr[tid + s] : 0.f;
        __syncthreads();
        arr[tid] += add;
        __syncthreads();
    }
    float denom = arr[0];
    float off = arr[tid] - mytotal;
    float r = 1.0f / denom;

    float4 o0 = make_float4((ls[0] + off) * r, (ls[1] + off) * r,
                            (ls[2] + off) * r, (ls[3] + off) * r);
    float4 o1 = make_float4((ls[4] + off) * r, (ls[5] + off) * r,
                            (ls[6] + off) * r, (ls[7] + off) * r);
    float4* po = (float4*)(t + tid * 8);
    po[0] = o0; po[1] = o1;
}

// K3c: part[jc,bh,u,d] = sum_{j in chunk jc} T[bh,u,j] * V[b,j,h,d]
__global__ __launch_bounds__(256) void k_ctx(const float* __restrict__ V,
                                             const float* __restrict__ T,
                                             float* __restrict__ part) {
    __shared__ float4 sT4[U * (JCL / 4)];   // 40 x 16 float4 = 10 KB
    int bh = blockIdx.x >> 5;               // JC = 32 chunks
    int jc = blockIdx.x & 31;
    int b = bh >> 3, h = bh & (H - 1);
    int tid = threadIdx.x;
    int d = tid & 63;
    int w = tid >> 6;

    const float4* Tg = (const float4*)(T + (size_t)bh * U * L);
    for (int i = tid; i < U * (JCL / 4); i += 256) {
        int u = i >> 4;          // JCL/4 = 16
        int c = i & 15;
        sT4[i] = Tg[u * (L / 4) + jc * (JCL / 4) + c];
    }
    __syncthreads();

    float acc[10];
#pragma unroll
    for (int uu = 0; uu < 10; ++uu) acc[uu] = 0.f;

    const float* Vb = V + (size_t)b * L * H * D + (size_t)h * D + d;
#pragma unroll 2
    for (int jj = 0; jj < JCL / 4; ++jj) {
        int j0 = jc * JCL + jj * 4;
        float v0 = Vb[(size_t)(j0 + 0) * (H * D)];
        float v1 = Vb[(size_t)(j0 + 1) * (H * D)];
        float v2 = Vb[(size_t)(j0 + 2) * (H * D)];
        float v3 = Vb[(size_t)(j0 + 3) * (H * D)];
#pragma unroll
        for (int uu = 0; uu < 10; ++uu) {
            float4 t4 = sT4[(w * 10 + uu) * 16 + jj];   // broadcast LDS read
            acc[uu] = fmaf(t4.x, v0, fmaf(t4.y, v1, fmaf(t4.z, v2, fmaf(t4.w, v3, acc[uu]))));
        }
    }

    float* po = part + ((size_t)jc * (B * H) + bh) * (U * D);
#pragma unroll
    for (int uu = 0; uu < 10; ++uu) po[(w * 10 + uu) * D + d] = acc[uu];
}

// final reduce over the JC j-chunks
__global__ __launch_bounds__(256) void k_red(const float* __restrict__ part,
                                             float* __restrict__ out) {
    int o = blockIdx.x * 256 + threadIdx.x;
    if (o >= B * H * U * D) return;
    int bh = o / (U * D);
    int rest = o - bh * (U * D);
    float s = 0.f;
#pragma unroll
    for (int jc = 0; jc < JC; ++jc)
        s += part[(size_t)(jc * (B * H) + bh) * (U * D) + rest];
    out[o] = s;
}

extern "C" void kernel_launch(void* const* d_in, const int* in_sizes, int n_in,
                              void* d_out, int out_size, void* d_ws, size_t ws_size,
                              hipStream_t stream) {
    const float* Q  = (const float*)d_in[0];
    const float* K  = (const float*)d_in[1];
    const float* V  = (const float*)d_in[2];
    const int* idx  = (const int*)d_in[3];
    float* out = (float*)d_out;

    float* M    = (float*)((char*)d_ws + OFF_M);
    int*   top  = (int*)  ((char*)d_ws + OFF_TOP);
    float* T    = (float*)((char*)d_ws + OFF_T);
    float* part = (float*)((char*)d_ws + OFF_PART);

    // K1: 512 q-quads x 8 (b,hh) groups; %8 pins (b,hh) to an XCD
    k_msamp<<<(L / 4) * 8, 256, 0, stream>>>(Q, K, idx, M);
    k_topk<<<B * H, 256, 0, stream>>>(M, top);
    k_scores<<<B * H * 16, 256, 0, stream>>>(Q, K, top, T);
    k_softsuf<<<B * H * U, 256, 0, stream>>>(T);
    k_ctx<<<B * H * JC, 256, 0, stream>>>(V, T, part);
    k_red<<<(B * H * U * D + 255) / 256, 256, 0, stream>>>(part, out);
}

// Round 6
// 162.889 us; speedup vs baseline: 2.3181x; 2.3181x over previous
//
#include <hip/hip_runtime.h>
#include <hip/hip_bf16.h>
#include <math.h>

#define B 4
#define L 2048
#define H 8
#define D 64
#define SK 40
#define U 40
#define JC 32          // j-chunks in k_ctx
#define JCL (L / JC)   // 64 j per chunk

// ws layout (bytes)
#define OFF_M    0                  // B*H*L floats = 262144 B
#define OFF_TOP  262144             // B*H*U ints  = 5120 B
#define OFF_T    270336             // B*H*U*L floats = 10485760 B
#define OFF_PART 10756096           // JC * B*H*U*D floats = 10485760 B  (end ~21.2 MB)

__device__ __forceinline__ float dot4(float4 a, float4 b) {
    return fmaf(a.x, b.x, fmaf(a.y, b.y, fmaf(a.z, b.z, a.w * b.w)));
}

// K1: M[b,h,q] = max_s dot(Q[bhq], K[bh,idx[q,s]]) - (1/L) * sum_s dot(...)
// XCD-locality: blockIdx%8 == b*2+hh pins each (b, h-half) to one XCD whose
// K working set is 2.1 MB < 4 MB L2.
__global__ __launch_bounds__(256) void k_msamp(const float* __restrict__ Q,
                                               const float* __restrict__ K,
                                               const int* __restrict__ idx,
                                               float* __restrict__ M) {
    int g  = blockIdx.x & 7;        // = b*2 + hh  (XCD id under %8 round-robin)
    int b  = g >> 1;
    int hh = g & 1;
    int t  = threadIdx.x;
    int q  = (blockIdx.x >> 3) * 4 + (t >> 6);
    int c  = t & 15;                // 16 c-chunks of 4 floats
    int hp = (t >> 4) & 3;          // h' within half
    int h  = hh * 4 + hp;

    float4 q4 = *((const float4*)(Q + (size_t)((b * L + q) * H + h) * D) + c);

    const int* ip = idx + q * SK;   // wave-uniform
    const float* kbase = K + (size_t)b * L * H * D + (size_t)h * D + c * 4;

    float vmax = -__builtin_inff();
    float vsum = 0.f;
#pragma unroll 8
    for (int s = 0; s < SK; ++s) {
        int kidx = ip[s];           // wave-uniform
        float4 k4 = *(const float4*)(kbase + (size_t)kidx * (H * D));
        float d4 = dot4(q4, k4);
        d4 += __shfl_xor(d4, 1, 64);
        d4 += __shfl_xor(d4, 2, 64);
        d4 += __shfl_xor(d4, 4, 64);
        d4 += __shfl_xor(d4, 8, 64);
        vmax = fmaxf(vmax, d4);
        vsum += d4;
    }
    if (c == 0) M[(size_t)(b * H + h) * L + q] = vmax - vsum * (1.0f / (float)L);
}

// K2: top-U per (b,h): min-max-normalized 256-bin select + exact candidate
// ranking. Order: value descending, ties -> lowest index (== jax.lax.top_k).
__global__ __launch_bounds__(256) void k_topk(const float* __restrict__ M,
                                              int* __restrict__ top) {
    __shared__ unsigned long long cand[L];    // worst-case candidates, 16 KB
    __shared__ unsigned int bins[256];
    __shared__ unsigned int red[256];
    __shared__ int cnt2;

    int bh = blockIdx.x;
    int tid = threadIdx.x;
    const float* m = M + (size_t)bh * L;

    bins[tid] = 0;
    if (tid == 0) cnt2 = 0;

    // load 8 values/thread, map to sortable uint, local min/max
    unsigned int u8[8];
    unsigned int umin = 0xFFFFFFFFu, umax = 0u;
#pragma unroll
    for (int e = 0; e < 8; ++e) {
        int i = tid * 8 + e;
        unsigned int bits = __float_as_uint(m[i]);
        unsigned int u = (bits & 0x80000000u) ? ~bits : (bits | 0x80000000u);
        u8[e] = u;
        umin = min(umin, u);
        umax = max(umax, u);
    }
    // block reduce min (red) and max (reuse via two phases)
    red[tid] = umin;
    __syncthreads();
    for (int s = 128; s; s >>= 1) {
        if (tid < s) red[tid] = min(red[tid], red[tid + s]);
        __syncthreads();
    }
    unsigned int kmin = red[0];
    __syncthreads();
    red[tid] = umax;
    __syncthreads();
    for (int s = 128; s; s >>= 1) {
        if (tid < s) red[tid] = max(red[tid], red[tid + s]);
        __syncthreads();
    }
    unsigned int kmax = red[0];
    __syncthreads();

    unsigned int range = kmax - kmin;
    if (range == 0u) {              // all equal: top-k = first U indices
        if (tid < U) top[bh * U + tid] = tid;
        return;
    }
    // shift so (range >> shift) <= 255
    int hb = 31 - __clz(range);
    int shift = (hb > 7) ? (hb - 7) : 0;

    // histogram normalized bins
#pragma unroll
    for (int e = 0; e < 8; ++e) {
        unsigned int bin = (u8[e] - kmin) >> shift;
        atomicAdd(&bins[bin], 1u);
    }
    __syncthreads();

    // inclusive suffix-sum: red[i] = #values in bins >= i
    red[tid] = bins[tid];
    __syncthreads();
    for (int s = 1; s < 256; s <<= 1) {
        unsigned int add = (tid + s < 256) ? red[tid + s] : 0u;
        __syncthreads();
        red[tid] += add;
        __syncthreads();
    }
    // t = max i with red[i] >= U  (red non-increasing; red[0] = 2048 >= U)
    int cnt = __syncthreads_count(red[tid] >= U);
    unsigned int t = (unsigned int)(cnt - 1);

    // collect candidates: all values in bins >= t
#pragma unroll
    for (int e = 0; e < 8; ++e) {
        unsigned int u = u8[e];
        if (((u - kmin) >> shift) >= t) {
            int pos = atomicAdd(&cnt2, 1);
            int i = tid * 8 + e;
            cand[pos] = ((unsigned long long)u << 11) | (unsigned long long)(2047 - i);
        }
    }
    __syncthreads();
    int C = cnt2;

    // exact rank of each candidate (keys all distinct); write top-U
    for (int j = tid; j < C; j += 256) {
        unsigned long long kj = cand[j];
        int r = 0;
        for (int kk = 0; kk < C; ++kk) r += (cand[kk] > kj);
        if (r < U) top[bh * U + r] = 2047 - (int)(kj & 0x7FFull);
    }
}

// K3a: T[bh,u,k] = 0.125 * dot(Q[bh, top[bh,u]], K[bh,k])
__global__ __launch_bounds__(256) void k_scores(const float* __restrict__ Q,
                                                const float* __restrict__ K,
                                                const int* __restrict__ top,
                                                float* __restrict__ T) {
    __shared__ float4 sQ4[U * 16];   // 40 rows x 64 floats = 10 KB
    int bh = blockIdx.x >> 4;        // 16 k-chunks
    int kc = blockIdx.x & 15;
    int b = bh >> 3, h = bh & (H - 1);
    int tid = threadIdx.x;
    int lane = tid & 63;
    int w = tid >> 6;

    for (int i = tid; i < U * 16; i += 256) {
        int u = i >> 4, c = i & 15;
        int qidx = top[bh * U + u];
        sQ4[i] = *((const float4*)(Q + (size_t)((b * L + qidx) * H + h) * D) + c);
    }

    int k0 = kc * 128 + lane;
    const float4* kr0 = (const float4*)(K + (size_t)((b * L + k0) * H + h) * D);
    const float4* kr1 = (const float4*)(K + (size_t)((b * L + k0 + 64) * H + h) * D);
    float4 kv0[16], kv1[16];
#pragma unroll
    for (int i = 0; i < 16; ++i) { kv0[i] = kr0[i]; kv1[i] = kr1[i]; }
    __syncthreads();

    float* Tb = T + (size_t)bh * U * L;
    for (int uu = 0; uu < 10; ++uu) {
        int u = w * 10 + uu;
        float s0 = 0.f, s1 = 0.f;
#pragma unroll
        for (int i = 0; i < 16; ++i) {
            float4 q4 = sQ4[u * 16 + i];   // broadcast LDS read
            s0 += dot4(q4, kv0[i]);
            s1 += dot4(q4, kv1[i]);
        }
        Tb[(size_t)u * L + k0]      = s0 * 0.125f;
        Tb[(size_t)u * L + k0 + 64] = s1 * 0.125f;
    }
}

// K3b: per row (bh,u): softmax over k then suffix-sum -> T[u,j] = sum_{k>=j} attn[k]
__global__ __launch_bounds__(256) void k_softsuf(float* __restrict__ T) {
    __shared__ float red[256];
    __shared__ float arr[256];
    int row = blockIdx.x;                  // [0, B*H*U)
    float* t = T + (size_t)row * L;
    int tid = threadIdx.x;

    const float4* p = (const float4*)(t + tid * 8);
    float4 a = p[0], c = p[1];
    float x[8] = {a.x, a.y, a.z, a.w, c.x, c.y, c.z, c.w};

    float mx = x[0];
#pragma unroll
    for (int i = 1; i < 8; ++i) mx = fmaxf(mx, x[i]);
    red[tid] = mx;
    __syncthreads();
    for (int s = 128; s; s >>= 1) {
        if (tid < s) red[tid] = fmaxf(red[tid], red[tid + s]);
        __syncthreads();
    }
    float maxv = red[0];
    __syncthreads();

    float e[8];
#pragma unroll
    for (int i = 0; i < 8; ++i) e[i] = __expf(x[i] - maxv);
    float ls[8];
    ls[7] = e[7];
#pragma unroll
    for (int i = 6; i >= 0; --i) ls[i] = e[i] + ls[i + 1];
    float mytotal = ls[0];

    arr[tid] = mytotal;
    __syncthreads();
    for (int s = 1; s < 256; s <<= 1) {
        float add = (tid + s < 256) ? arr[tid + s] : 0.f;
        __syncthreads();
        arr[tid] += add;
        __syncthreads();
    }
    float denom = arr[0];
    float off = arr[tid] - mytotal;
    float r = 1.0f / denom;

    float4 o0 = make_float4((ls[0] + off) * r, (ls[1] + off) * r,
                            (ls[2] + off) * r, (ls[3] + off) * r);
    float4 o1 = make_float4((ls[4] + off) * r, (ls[5] + off) * r,
                            (ls[6] + off) * r, (ls[7] + off) * r);
    float4* po = (float4*)(t + tid * 8);
    po[0] = o0; po[1] = o1;
}

// K3c: part[jc,bh,u,d] = sum_{j in chunk jc} T[bh,u,j] * V[b,j,h,d]
__global__ __launch_bounds__(256) void k_ctx(const float* __restrict__ V,
                                             const float* __restrict__ T,
                                             float* __restrict__ part) {
    __shared__ float4 sT4[U * (JCL / 4)];   // 40 x 16 float4 = 10 KB
    int bh = blockIdx.x >> 5;               // JC = 32 chunks
    int jc = blockIdx.x & 31;
    int b = bh >> 3, h = bh & (H - 1);
    int tid = threadIdx.x;
    int d = tid & 63;
    int w = tid >> 6;

    const float4* Tg = (const float4*)(T + (size_t)bh * U * L);
    for (int i = tid; i < U * (JCL / 4); i += 256) {
        int u = i >> 4;          // JCL/4 = 16
        int c = i & 15;
        sT4[i] = Tg[u * (L / 4) + jc * (JCL / 4) + c];
    }
    __syncthreads();

    float acc[10];
#pragma unroll
    for (int uu = 0; uu < 10; ++uu) acc[uu] = 0.f;

    const float* Vb = V + (size_t)b * L * H * D + (size_t)h * D + d;
#pragma unroll 2
    for (int jj = 0; jj < JCL / 4; ++jj) {
        int j0 = jc * JCL + jj * 4;
        float v0 = Vb[(size_t)(j0 + 0) * (H * D)];
        float v1 = Vb[(size_t)(j0 + 1) * (H * D)];
        float v2 = Vb[(size_t)(j0 + 2) * (H * D)];
        float v3 = Vb[(size_t)(j0 + 3) * (H * D)];
#pragma unroll
        for (int uu = 0; uu < 10; ++uu) {
            float4 t4 = sT4[(w * 10 + uu) * 16 + jj];   // broadcast LDS read
            acc[uu] = fmaf(t4.x, v0, fmaf(t4.y, v1, fmaf(t4.z, v2, fmaf(t4.w, v3, acc[uu]))));
        }
    }

    float* po = part + ((size_t)jc * (B * H) + bh) * (U * D);
#pragma unroll
    for (int uu = 0; uu < 10; ++uu) po[(w * 10 + uu) * D + d] = acc[uu];
}

// final reduce over the JC j-chunks
__global__ __launch_bounds__(256) void k_red(const float* __restrict__ part,
                                             float* __restrict__ out) {
    int o = blockIdx.x * 256 + threadIdx.x;
    if (o >= B * H * U * D) return;
    int bh = o / (U * D);
    int rest = o - bh * (U * D);
    float s = 0.f;
#pragma unroll
    for (int jc = 0; jc < JC; ++jc)
        s += part[(size_t)(jc * (B * H) + bh) * (U * D) + rest];
    out[o] = s;
}

extern "C" void kernel_launch(void* const* d_in, const int* in_sizes, int n_in,
                              void* d_out, int out_size, void* d_ws, size_t ws_size,
                              hipStream_t stream) {
    const float* Q  = (const float*)d_in[0];
    const float* K  = (const float*)d_in[1];
    const float* V  = (const float*)d_in[2];
    const int* idx  = (const int*)d_in[3];
    float* out = (float*)d_out;

    float* M    = (float*)((char*)d_ws + OFF_M);
    int*   top  = (int*)  ((char*)d_ws + OFF_TOP);
    float* T    = (float*)((char*)d_ws + OFF_T);
    float* part = (float*)((char*)d_ws + OFF_PART);

    // K1: 512 q-quads x 8 (b,hh) groups; %8 pins (b,hh) to an XCD
    k_msamp<<<(L / 4) * 8, 256, 0, stream>>>(Q, K, idx, M);
    k_topk<<<B * H, 256, 0, stream>>>(M, top);
    k_scores<<<B * H * 16, 256, 0, stream>>>(Q, K, top, T);
    k_softsuf<<<B * H * U, 256, 0, stream>>>(T);
    k_ctx<<<B * H * JC, 256, 0, stream>>>(V, T, part);
    k_red<<<(B * H * U * D + 255) / 256, 256, 0, stream>>>(part, out);
}

// Round 7
// 156.544 us; speedup vs baseline: 2.4121x; 1.0405x over previous
//
#include <hip/hip_runtime.h>
#include <hip/hip_bf16.h>
#include <math.h>

#define B 4
#define L 2048
#define H 8
#define D 64
#define SK 40
#define U 40
#define JC 32          // j-chunks in k_ctx
#define JCL (L / JC)   // 64 j per chunk

// ws layout (bytes)
#define OFF_M    0                  // B*H*L floats = 262144 B
#define OFF_TOP  262144             // B*H*U ints  = 5120 B
#define OFF_T    270336             // B*H*U*L floats = 10485760 B
#define OFF_PART 10756096           // JC * B*H*U*D floats = 10485760 B  (end ~21.2 MB)

__device__ __forceinline__ float dot4(float4 a, float4 b) {
    return fmaf(a.x, b.x, fmaf(a.y, b.y, fmaf(a.z, b.z, a.w * b.w)));
}

// K1: M[b,h,q] = max_s dot(Q[bhq], K[bh,idx[q,s]]) - (1/L) * sum_s dot(...)
// XCD-locality: blockIdx%8 == b*2+hh pins each (b, h-half) to one XCD whose
// K working set is 2.1 MB < 4 MB L2.
// Wave = 2 queries (2 independent gather streams); lane = qp*32 + hp*8 + c8.
// idx rows preloaded into regs and broadcast via shuffles so all K-row
// addresses are known up front (deep VMEM pipelining).
__global__ __launch_bounds__(256) void k_msamp(const float* __restrict__ Q,
                                               const float* __restrict__ K,
                                               const int* __restrict__ idx,
                                               float* __restrict__ M) {
    int g  = blockIdx.x & 7;        // = b*2 + hh  (XCD id under %8 round-robin)
    int b  = g >> 1;
    int hh = g & 1;
    int t  = threadIdx.x;
    int wave = t >> 6;
    int lane = t & 63;
    int qp = lane >> 5;             // 0/1: which query of this wave
    int hp = (lane >> 3) & 3;       // h' within half
    int c  = lane & 7;              // 8-float chunk of D
    int h  = hh * 4 + hp;
    int q  = (blockIdx.x >> 3) * 8 + wave * 2 + qp;

    const float* qrow = Q + (size_t)((b * L + q) * H + h) * D + c * 8;
    float4 qa = *(const float4*)qrow;
    float4 qb = *(const float4*)(qrow + 4);

    // preload idx[q][*]: lanes 0..31 hold q0's s=0..31 / lanes 32..63 q1's
    int s1 = lane & 31;
    int v1 = idx[q * SK + s1];
    int s2 = 32 + s1; if (s2 > SK - 1) s2 = SK - 1;   // clamp (dup, unused)
    int v2 = idx[q * SK + s2];

    const float* kbase = K + (size_t)b * L * H * D + (size_t)h * D + c * 8;

    float vmax = -__builtin_inff();
    float vsum = 0.f;
#pragma unroll 8
    for (int s = 0; s < SK; ++s) {
        int kidx = (s < 32) ? __shfl(v1, qp * 32 + s, 64)
                            : __shfl(v2, qp * 32 + (s - 32), 64);
        const float* kp = kbase + (size_t)kidx * (H * D);
        float4 ka = *(const float4*)kp;
        float4 kb = *(const float4*)(kp + 4);
        float d8 = dot4(qa, ka) + dot4(qb, kb);
        // reduce across the 8 c-lanes (same q, same h)
        d8 += __shfl_xor(d8, 1, 64);
        d8 += __shfl_xor(d8, 2, 64);
        d8 += __shfl_xor(d8, 4, 64);
        vmax = fmaxf(vmax, d8);
        vsum += d8;
    }
    if (c == 0) M[(size_t)(b * H + h) * L + q] = vmax - vsum * (1.0f / (float)L);
}

// K2: top-U per (b,h): min-max-normalized 256-bin select + exact candidate
// ranking. Order: value descending, ties -> lowest index (== jax.lax.top_k).
__global__ __launch_bounds__(256) void k_topk(const float* __restrict__ M,
                                              int* __restrict__ top) {
    __shared__ unsigned long long cand[L];    // worst-case candidates, 16 KB
    __shared__ unsigned int bins[256];
    __shared__ unsigned int red[256];
    __shared__ int cnt2;

    int bh = blockIdx.x;
    int tid = threadIdx.x;
    const float* m = M + (size_t)bh * L;

    bins[tid] = 0;
    if (tid == 0) cnt2 = 0;

    // load 8 values/thread, map to sortable uint, local min/max
    unsigned int u8[8];
    unsigned int umin = 0xFFFFFFFFu, umax = 0u;
#pragma unroll
    for (int e = 0; e < 8; ++e) {
        int i = tid * 8 + e;
        unsigned int bits = __float_as_uint(m[i]);
        unsigned int u = (bits & 0x80000000u) ? ~bits : (bits | 0x80000000u);
        u8[e] = u;
        umin = min(umin, u);
        umax = max(umax, u);
    }
    red[tid] = umin;
    __syncthreads();
    for (int s = 128; s; s >>= 1) {
        if (tid < s) red[tid] = min(red[tid], red[tid + s]);
        __syncthreads();
    }
    unsigned int kmin = red[0];
    __syncthreads();
    red[tid] = umax;
    __syncthreads();
    for (int s = 128; s; s >>= 1) {
        if (tid < s) red[tid] = max(red[tid], red[tid + s]);
        __syncthreads();
    }
    unsigned int kmax = red[0];
    __syncthreads();

    unsigned int range = kmax - kmin;
    if (range == 0u) {              // all equal: top-k = first U indices
        if (tid < U) top[bh * U + tid] = tid;
        return;
    }
    int hb = 31 - __clz(range);
    int shift = (hb > 7) ? (hb - 7) : 0;

#pragma unroll
    for (int e = 0; e < 8; ++e) {
        unsigned int bin = (u8[e] - kmin) >> shift;
        atomicAdd(&bins[bin], 1u);
    }
    __syncthreads();

    // inclusive suffix-sum: red[i] = #values in bins >= i
    red[tid] = bins[tid];
    __syncthreads();
    for (int s = 1; s < 256; s <<= 1) {
        unsigned int add = (tid + s < 256) ? red[tid + s] : 0u;
        __syncthreads();
        red[tid] += add;
        __syncthreads();
    }
    int cnt = __syncthreads_count(red[tid] >= U);
    unsigned int t = (unsigned int)(cnt - 1);

#pragma unroll
    for (int e = 0; e < 8; ++e) {
        unsigned int u = u8[e];
        if (((u - kmin) >> shift) >= t) {
            int pos = atomicAdd(&cnt2, 1);
            int i = tid * 8 + e;
            cand[pos] = ((unsigned long long)u << 11) | (unsigned long long)(2047 - i);
        }
    }
    __syncthreads();
    int C = cnt2;

    for (int j = tid; j < C; j += 256) {
        unsigned long long kj = cand[j];
        int r = 0;
        for (int kk = 0; kk < C; ++kk) r += (cand[kk] > kj);
        if (r < U) top[bh * U + r] = 2047 - (int)(kj & 0x7FFull);
    }
}

// K3a: T[bh,u,k] = 0.125 * dot(Q[bh, top[bh,u]], K[bh,k])
__global__ __launch_bounds__(256) void k_scores(const float* __restrict__ Q,
                                                const float* __restrict__ K,
                                                const int* __restrict__ top,
                                                float* __restrict__ T) {
    __shared__ float4 sQ4[U * 16];   // 40 rows x 64 floats = 10 KB
    int bh = blockIdx.x >> 4;        // 16 k-chunks
    int kc = blockIdx.x & 15;
    int b = bh >> 3, h = bh & (H - 1);
    int tid = threadIdx.x;
    int lane = tid & 63;
    int w = tid >> 6;

    for (int i = tid; i < U * 16; i += 256) {
        int u = i >> 4, c = i & 15;
        int qidx = top[bh * U + u];
        sQ4[i] = *((const float4*)(Q + (size_t)((b * L + qidx) * H + h) * D) + c);
    }

    int k0 = kc * 128 + lane;
    const float4* kr0 = (const float4*)(K + (size_t)((b * L + k0) * H + h) * D);
    const float4* kr1 = (const float4*)(K + (size_t)((b * L + k0 + 64) * H + h) * D);
    float4 kv0[16], kv1[16];
#pragma unroll
    for (int i = 0; i < 16; ++i) { kv0[i] = kr0[i]; kv1[i] = kr1[i]; }
    __syncthreads();

    float* Tb = T + (size_t)bh * U * L;
    for (int uu = 0; uu < 10; ++uu) {
        int u = w * 10 + uu;
        float s0 = 0.f, s1 = 0.f;
#pragma unroll
        for (int i = 0; i < 16; ++i) {
            float4 q4 = sQ4[u * 16 + i];   // broadcast LDS read
            s0 += dot4(q4, kv0[i]);
            s1 += dot4(q4, kv1[i]);
        }
        Tb[(size_t)u * L + k0]      = s0 * 0.125f;
        Tb[(size_t)u * L + k0 + 64] = s1 * 0.125f;
    }
}

// K3b: per row (bh,u): softmax over k then suffix-sum -> T[u,j] = sum_{k>=j} attn[k]
__global__ __launch_bounds__(256) void k_softsuf(float* __restrict__ T) {
    __shared__ float red[256];
    __shared__ float arr[256];
    int row = blockIdx.x;                  // [0, B*H*U)
    float* t = T + (size_t)row * L;
    int tid = threadIdx.x;

    const float4* p = (const float4*)(t + tid * 8);
    float4 a = p[0], c = p[1];
    float x[8] = {a.x, a.y, a.z, a.w, c.x, c.y, c.z, c.w};

    float mx = x[0];
#pragma unroll
    for (int i = 1; i < 8; ++i) mx = fmaxf(mx, x[i]);
    red[tid] = mx;
    __syncthreads();
    for (int s = 128; s; s >>= 1) {
        if (tid < s) red[tid] = fmaxf(red[tid], red[tid + s]);
        __syncthreads();
    }
    float maxv = red[0];
    __syncthreads();

    float e[8];
#pragma unroll
    for (int i = 0; i < 8; ++i) e[i] = __expf(x[i] - maxv);
    float ls[8];
    ls[7] = e[7];
#pragma unroll
    for (int i = 6; i >= 0; --i) ls[i] = e[i] + ls[i + 1];
    float mytotal = ls[0];

    arr[tid] = mytotal;
    __syncthreads();
    for (int s = 1; s < 256; s <<= 1) {
        float add = (tid + s < 256) ? arr[tid + s] : 0.f;
        __syncthreads();
        arr[tid] += add;
        __syncthreads();
    }
    float denom = arr[0];
    float off = arr[tid] - mytotal;
    float r = 1.0f / denom;

    float4 o0 = make_float4((ls[0] + off) * r, (ls[1] + off) * r,
                            (ls[2] + off) * r, (ls[3] + off) * r);
    float4 o1 = make_float4((ls[4] + off) * r, (ls[5] + off) * r,
                            (ls[6] + off) * r, (ls[7] + off) * r);
    float4* po = (float4*)(t + tid * 8);
    po[0] = o0; po[1] = o1;
}

// K3c: part[jc,bh,u,d] = sum_{j in chunk jc} T[bh,u,j] * V[b,j,h,d]
// lane = j2(2b) x d4(4b): V read as float4 along d (4 j rows per wave-instr);
// T broadcast via ds_read_b32; cross-j2 reduce with 2 shuffle-xors.
__global__ __launch_bounds__(256) void k_ctx(const float* __restrict__ V,
                                             const float* __restrict__ T,
                                             float* __restrict__ part) {
    __shared__ float sT[U][JCL];            // 40 x 64 floats = 10 KB
    int bh = blockIdx.x >> 5;               // JC = 32 chunks
    int jc = blockIdx.x & 31;
    int b = bh >> 3, h = bh & (H - 1);
    int tid = threadIdx.x;
    int w = tid >> 6;                       // wave: u in [10w, 10w+10)
    int lane = tid & 63;
    int j2 = lane >> 4;                     // 0..3 j-subgroup
    int d4 = lane & 15;                     // float4 index along d

    const float* Tg = T + (size_t)bh * U * L + jc * JCL;
    float4* sT4 = (float4*)sT;
    for (int i = tid; i < U * (JCL / 4); i += 256) {
        int u = i >> 4, cc = i & 15;
        sT4[i] = ((const float4*)(Tg + (size_t)u * L))[cc];
    }
    __syncthreads();

    float4 acc[10];
#pragma unroll
    for (int uu = 0; uu < 10; ++uu) acc[uu] = make_float4(0.f, 0.f, 0.f, 0.f);

    const float* Vb = V + (size_t)(b * L) * (H * D) + (size_t)h * D + d4 * 4;
#pragma unroll 4
    for (int it = 0; it < JCL / 4; ++it) {
        int j = it * 4 + j2;
        float4 v4 = *(const float4*)(Vb + (size_t)(jc * JCL + j) * (H * D));
#pragma unroll
        for (int uu = 0; uu < 10; ++uu) {
            float tj = sT[w * 10 + uu][j];   // 4-way broadcast LDS read
            acc[uu].x = fmaf(tj, v4.x, acc[uu].x);
            acc[uu].y = fmaf(tj, v4.y, acc[uu].y);
            acc[uu].z = fmaf(tj, v4.z, acc[uu].z);
            acc[uu].w = fmaf(tj, v4.w, acc[uu].w);
        }
    }

    float* po = part + ((size_t)jc * (B * H) + bh) * (U * D);
#pragma unroll
    for (int uu = 0; uu < 10; ++uu) {
        float4 a = acc[uu];
        a.x += __shfl_xor(a.x, 16, 64); a.y += __shfl_xor(a.y, 16, 64);
        a.z += __shfl_xor(a.z, 16, 64); a.w += __shfl_xor(a.w, 16, 64);
        a.x += __shfl_xor(a.x, 32, 64); a.y += __shfl_xor(a.y, 32, 64);
        a.z += __shfl_xor(a.z, 32, 64); a.w += __shfl_xor(a.w, 32, 64);
        if (j2 == 0) *(float4*)(po + (w * 10 + uu) * D + d4 * 4) = a;
    }
}

// final reduce over the JC j-chunks
__global__ __launch_bounds__(256) void k_red(const float* __restrict__ part,
                                             float* __restrict__ out) {
    int o = blockIdx.x * 256 + threadIdx.x;
    if (o >= B * H * U * D) return;
    int bh = o / (U * D);
    int rest = o - bh * (U * D);
    float s = 0.f;
#pragma unroll
    for (int jc = 0; jc < JC; ++jc)
        s += part[(size_t)(jc * (B * H) + bh) * (U * D) + rest];
    out[o] = s;
}

extern "C" void kernel_launch(void* const* d_in, const int* in_sizes, int n_in,
                              void* d_out, int out_size, void* d_ws, size_t ws_size,
                              hipStream_t stream) {
    const float* Q  = (const float*)d_in[0];
    const float* K  = (const float*)d_in[1];
    const float* V  = (const float*)d_in[2];
    const int* idx  = (const int*)d_in[3];
    float* out = (float*)d_out;

    float* M    = (float*)((char*)d_ws + OFF_M);
    int*   top  = (int*)  ((char*)d_ws + OFF_TOP);
    float* T    = (float*)((char*)d_ws + OFF_T);
    float* part = (float*)((char*)d_ws + OFF_PART);

    // K1: 256 q-octets x 8 (b,hh) groups; %8 pins (b,hh) to an XCD
    k_msamp<<<(L / 8) * 8, 256, 0, stream>>>(Q, K, idx, M);
    k_topk<<<B * H, 256, 0, stream>>>(M, top);
    k_scores<<<B * H * 16, 256, 0, stream>>>(Q, K, top, T);
    k_softsuf<<<B * H * U, 256, 0, stream>>>(T);
    k_ctx<<<B * H * JC, 256, 0, stream>>>(V, T, part);
    k_red<<<(B * H * U * D + 255) / 256, 256, 0, stream>>>(part, out);
}

// Round 8
// 150.033 us; speedup vs baseline: 2.5167x; 1.0434x over previous
//
#include <hip/hip_runtime.h>
#include <hip/hip_bf16.h>
#include <math.h>

#define B 4
#define L 2048
#define H 8
#define D 64
#define SK 40
#define U 40
#define JC 32          // j-chunks in k_ctx
#define JCL (L / JC)   // 64 j per chunk

// ws layout (bytes)
#define OFF_M     0                  // B*H*L floats = 262144 B
#define OFF_TOP   262144             // B*H*U ints  = 5120 B
#define OFF_T     270336             // B*H*U*L floats (E matrix) = 10485760 B
#define OFF_PART  10756096           // JC * B*H*U*D floats = 10485760 B
#define OFF_CSUM  21241856           // B*H*U*JC floats = 163840 B
#define OFF_TAILS 21405696           // B*H*U*JC floats = 163840 B
#define OFF_RDEN  21569536           // B*H*U floats = 5120 B (end ~21.6 MB)

__device__ __forceinline__ float dot4(float4 a, float4 b) {
    return fmaf(a.x, b.x, fmaf(a.y, b.y, fmaf(a.z, b.z, a.w * b.w)));
}

// K1: M[b,h,q] = max_s dot(Q[bhq], K[bh,idx[q,s]]) - (1/L) * sum_s dot(...)
// XCD-locality: blockIdx%8 == b*2+hh pins each (b, h-half) to one XCD whose
// K working set is 2.1 MB < 4 MB L2. Wave = 2 queries; idx preloaded to regs
// and broadcast via shuffles for deep VMEM pipelining.
__global__ __launch_bounds__(256) void k_msamp(const float* __restrict__ Q,
                                               const float* __restrict__ K,
                                               const int* __restrict__ idx,
                                               float* __restrict__ M) {
    int g  = blockIdx.x & 7;        // = b*2 + hh  (XCD id under %8 round-robin)
    int b  = g >> 1;
    int hh = g & 1;
    int t  = threadIdx.x;
    int wave = t >> 6;
    int lane = t & 63;
    int qp = lane >> 5;             // 0/1: which query of this wave
    int hp = (lane >> 3) & 3;       // h' within half
    int c  = lane & 7;              // 8-float chunk of D
    int h  = hh * 4 + hp;
    int q  = (blockIdx.x >> 3) * 8 + wave * 2 + qp;

    const float* qrow = Q + (size_t)((b * L + q) * H + h) * D + c * 8;
    float4 qa = *(const float4*)qrow;
    float4 qb = *(const float4*)(qrow + 4);

    int s1 = lane & 31;
    int v1 = idx[q * SK + s1];
    int s2 = 32 + s1; if (s2 > SK - 1) s2 = SK - 1;   // clamp (dup, unused)
    int v2 = idx[q * SK + s2];

    const float* kbase = K + (size_t)b * L * H * D + (size_t)h * D + c * 8;

    float vmax = -__builtin_inff();
    float vsum = 0.f;
#pragma unroll 8
    for (int s = 0; s < SK; ++s) {
        int kidx = (s < 32) ? __shfl(v1, qp * 32 + s, 64)
                            : __shfl(v2, qp * 32 + (s - 32), 64);
        const float* kp = kbase + (size_t)kidx * (H * D);
        float4 ka = *(const float4*)kp;
        float4 kb = *(const float4*)(kp + 4);
        float d8 = dot4(qa, ka) + dot4(qb, kb);
        d8 += __shfl_xor(d8, 1, 64);
        d8 += __shfl_xor(d8, 2, 64);
        d8 += __shfl_xor(d8, 4, 64);
        vmax = fmaxf(vmax, d8);
        vsum += d8;
    }
    if (c == 0) M[(size_t)(b * H + h) * L + q] = vmax - vsum * (1.0f / (float)L);
}

// K2: top-U per (b,h): min-max-normalized 256-bin select + exact candidate
// ranking. Order: value descending, ties -> lowest index (== jax.lax.top_k).
__global__ __launch_bounds__(256) void k_topk(const float* __restrict__ M,
                                              int* __restrict__ top) {
    __shared__ unsigned long long cand[L];    // worst-case candidates, 16 KB
    __shared__ unsigned int bins[256];
    __shared__ unsigned int red[256];
    __shared__ int cnt2;

    int bh = blockIdx.x;
    int tid = threadIdx.x;
    const float* m = M + (size_t)bh * L;

    bins[tid] = 0;
    if (tid == 0) cnt2 = 0;

    // load 8 values/thread (2x float4), map to sortable uint, local min/max
    const float4* m4 = (const float4*)(m + tid * 8);
    float4 fa = m4[0], fb = m4[1];
    float f8[8] = {fa.x, fa.y, fa.z, fa.w, fb.x, fb.y, fb.z, fb.w};
    unsigned int u8[8];
    unsigned int umin = 0xFFFFFFFFu, umax = 0u;
#pragma unroll
    for (int e = 0; e < 8; ++e) {
        unsigned int bits = __float_as_uint(f8[e]);
        unsigned int u = (bits & 0x80000000u) ? ~bits : (bits | 0x80000000u);
        u8[e] = u;
        umin = min(umin, u);
        umax = max(umax, u);
    }
    red[tid] = umin;
    __syncthreads();
    for (int s = 128; s; s >>= 1) {
        if (tid < s) red[tid] = min(red[tid], red[tid + s]);
        __syncthreads();
    }
    unsigned int kmin = red[0];
    __syncthreads();
    red[tid] = umax;
    __syncthreads();
    for (int s = 128; s; s >>= 1) {
        if (tid < s) red[tid] = max(red[tid], red[tid + s]);
        __syncthreads();
    }
    unsigned int kmax = red[0];
    __syncthreads();

    unsigned int range = kmax - kmin;
    if (range == 0u) {              // all equal: top-k = first U indices
        if (tid < U) top[bh * U + tid] = tid;
        return;
    }
    int hb = 31 - __clz(range);
    int shift = (hb > 7) ? (hb - 7) : 0;

#pragma unroll
    for (int e = 0; e < 8; ++e) {
        unsigned int bin = (u8[e] - kmin) >> shift;
        atomicAdd(&bins[bin], 1u);
    }
    __syncthreads();

    // inclusive suffix-sum: red[i] = #values in bins >= i
    red[tid] = bins[tid];
    __syncthreads();
    for (int s = 1; s < 256; s <<= 1) {
        unsigned int add = (tid + s < 256) ? red[tid + s] : 0u;
        __syncthreads();
        red[tid] += add;
        __syncthreads();
    }
    int cnt = __syncthreads_count(red[tid] >= U);
    unsigned int t = (unsigned int)(cnt - 1);

#pragma unroll
    for (int e = 0; e < 8; ++e) {
        unsigned int u = u8[e];
        if (((u - kmin) >> shift) >= t) {
            int pos = atomicAdd(&cnt2, 1);
            int i = tid * 8 + e;
            cand[pos] = ((unsigned long long)u << 11) | (unsigned long long)(2047 - i);
        }
    }
    __syncthreads();
    int C = cnt2;

    for (int j = tid; j < C; j += 256) {
        unsigned long long kj = cand[j];
        int r = 0;
        for (int kk = 0; kk < C; ++kk) r += (cand[kk] > kj);
        if (r < U) top[bh * U + r] = 2047 - (int)(kj & 0x7FFull);
    }
}

// K3a: E[bh,u,k] = exp(0.125 * dot(Q[bh, top[bh,u]], K[bh,k]))   (no max-sub:
// |score| <~ 6 so exp is fp32-safe; softmax normalization applied in k_red)
// Also emits csum[bh][u][jc] = sum of E over each 64-col chunk.
__global__ __launch_bounds__(256) void k_scores(const float* __restrict__ Q,
                                                const float* __restrict__ K,
                                                const int* __restrict__ top,
                                                float* __restrict__ T,
                                                float* __restrict__ csum) {
    __shared__ float4 sQ4[U * 16];   // 40 rows x 64 floats = 10 KB
    int bh = blockIdx.x >> 4;        // 16 k-chunks of 128
    int kc = blockIdx.x & 15;
    int b = bh >> 3, h = bh & (H - 1);
    int tid = threadIdx.x;
    int lane = tid & 63;
    int w = tid >> 6;

    for (int i = tid; i < U * 16; i += 256) {
        int u = i >> 4, c = i & 15;
        int qidx = top[bh * U + u];
        sQ4[i] = *((const float4*)(Q + (size_t)((b * L + qidx) * H + h) * D) + c);
    }

    int k0 = kc * 128 + lane;
    const float4* kr0 = (const float4*)(K + (size_t)((b * L + k0) * H + h) * D);
    const float4* kr1 = (const float4*)(K + (size_t)((b * L + k0 + 64) * H + h) * D);
    float4 kv0[16], kv1[16];
#pragma unroll
    for (int i = 0; i < 16; ++i) { kv0[i] = kr0[i]; kv1[i] = kr1[i]; }
    __syncthreads();

    float* Tb = T + (size_t)bh * U * L;
    for (int uu = 0; uu < 10; ++uu) {
        int u = w * 10 + uu;
        float s0 = 0.f, s1 = 0.f;
#pragma unroll
        for (int i = 0; i < 16; ++i) {
            float4 q4 = sQ4[u * 16 + i];   // broadcast LDS read
            s0 += dot4(q4, kv0[i]);
            s1 += dot4(q4, kv1[i]);
        }
        float e0 = __expf(s0 * 0.125f);
        float e1 = __expf(s1 * 0.125f);
        Tb[(size_t)u * L + k0]      = e0;
        Tb[(size_t)u * L + k0 + 64] = e1;
        // per-64-chunk sums (chunks 2*kc and 2*kc+1)
        float c0 = e0, c1 = e1;
#pragma unroll
        for (int o = 1; o < 64; o <<= 1) {
            c0 += __shfl_xor(c0, o, 64);
            c1 += __shfl_xor(c1, o, 64);
        }
        if (lane == 0) {
            csum[((size_t)bh * U + u) * JC + 2 * kc]     = c0;
            csum[((size_t)bh * U + u) * JC + 2 * kc + 1] = c1;
        }
    }
}

// K3b': per row: suffix over the 32 chunk sums -> tails[jc] = sum beyond
// chunk jc; rden = 1/denominator.
__global__ __launch_bounds__(64) void k_tails(const float* __restrict__ csum,
                                              float* __restrict__ tails,
                                              float* __restrict__ rden) {
    int bh = blockIdx.x;
    int r = threadIdx.x;
    if (r < U) {
        size_t base = ((size_t)bh * U + r) * JC;
        float acc = 0.f;
#pragma unroll
        for (int j = JC - 1; j >= 0; --j) {
            tails[base + j] = acc;
            acc += csum[base + j];
        }
        rden[bh * U + r] = 1.0f / acc;
    }
}

// K3c: part[jc,bh,u,d] = sum_{j in chunk jc} Tsuf[u,j] * V[b,j,h,d] where
// Tsuf[u,j] = (within-chunk inclusive suffix of E) + tails[u][jc].
// Row width 64 == wave width: suffix scan done in registers via shfl_down.
__global__ __launch_bounds__(256) void k_ctx(const float* __restrict__ V,
                                             const float* __restrict__ E,
                                             const float* __restrict__ tails,
                                             float* __restrict__ part) {
    __shared__ float sT[U][JCL];            // 40 x 64 floats = 10 KB
    int bh = blockIdx.x >> 5;               // JC = 32 chunks
    int jc = blockIdx.x & 31;
    int b = bh >> 3, h = bh & (H - 1);
    int tid = threadIdx.x;
    int w = tid >> 6;                       // wave: u in [10w, 10w+10)
    int lane = tid & 63;
    int j2 = lane >> 4;                     // 0..3 j-subgroup
    int d4 = lane & 15;                     // float4 index along d

    const float* Eg = E + (size_t)bh * U * L + jc * JCL;
#pragma unroll
    for (int r = 0; r < 10; ++r) {
        int u = w * 10 + r;
        float v = Eg[(size_t)u * L + lane];
        // 6-step inclusive suffix scan across the wave
#pragma unroll
        for (int s = 1; s < 64; s <<= 1) {
            float o = __shfl_down(v, s, 64);
            v += (lane + s < 64) ? o : 0.f;
        }
        v += tails[((size_t)bh * U + u) * JC + jc];   // wave-uniform
        sT[u][lane] = v;
    }
    __syncthreads();

    float4 acc[10];
#pragma unroll
    for (int uu = 0; uu < 10; ++uu) acc[uu] = make_float4(0.f, 0.f, 0.f, 0.f);

    const float* Vb = V + (size_t)(b * L) * (H * D) + (size_t)h * D + d4 * 4;
#pragma unroll 4
    for (int it = 0; it < JCL / 4; ++it) {
        int j = it * 4 + j2;
        float4 v4 = *(const float4*)(Vb + (size_t)(jc * JCL + j) * (H * D));
#pragma unroll
        for (int uu = 0; uu < 10; ++uu) {
            float tj = sT[w * 10 + uu][j];   // broadcast LDS read
            acc[uu].x = fmaf(tj, v4.x, acc[uu].x);
            acc[uu].y = fmaf(tj, v4.y, acc[uu].y);
            acc[uu].z = fmaf(tj, v4.z, acc[uu].z);
            acc[uu].w = fmaf(tj, v4.w, acc[uu].w);
        }
    }

    float* po = part + ((size_t)jc * (B * H) + bh) * (U * D);
#pragma unroll
    for (int uu = 0; uu < 10; ++uu) {
        float4 a = acc[uu];
        a.x += __shfl_xor(a.x, 16, 64); a.y += __shfl_xor(a.y, 16, 64);
        a.z += __shfl_xor(a.z, 16, 64); a.w += __shfl_xor(a.w, 16, 64);
        a.x += __shfl_xor(a.x, 32, 64); a.y += __shfl_xor(a.y, 32, 64);
        a.z += __shfl_xor(a.z, 32, 64); a.w += __shfl_xor(a.w, 32, 64);
        if (j2 == 0) *(float4*)(po + (w * 10 + uu) * D + d4 * 4) = a;
    }
}

// final reduce over the JC j-chunks + softmax normalization
__global__ __launch_bounds__(256) void k_red(const float* __restrict__ part,
                                             const float* __restrict__ rden,
                                             float* __restrict__ out) {
    int o = blockIdx.x * 256 + threadIdx.x;
    if (o >= B * H * U * D) return;
    int bh = o / (U * D);
    int rest = o - bh * (U * D);
    int u = rest >> 6;
    float s = 0.f;
#pragma unroll
    for (int jc = 0; jc < JC; ++jc)
        s += part[(size_t)(jc * (B * H) + bh) * (U * D) + rest];
    out[o] = s * rden[bh * U + u];
}

extern "C" void kernel_launch(void* const* d_in, const int* in_sizes, int n_in,
                              void* d_out, int out_size, void* d_ws, size_t ws_size,
                              hipStream_t stream) {
    const float* Q  = (const float*)d_in[0];
    const float* K  = (const float*)d_in[1];
    const float* V  = (const float*)d_in[2];
    const int* idx  = (const int*)d_in[3];
    float* out = (float*)d_out;

    float* M     = (float*)((char*)d_ws + OFF_M);
    int*   top   = (int*)  ((char*)d_ws + OFF_TOP);
    float* T     = (float*)((char*)d_ws + OFF_T);
    float* part  = (float*)((char*)d_ws + OFF_PART);
    float* csum  = (float*)((char*)d_ws + OFF_CSUM);
    float* tails = (float*)((char*)d_ws + OFF_TAILS);
    float* rden  = (float*)((char*)d_ws + OFF_RDEN);

    // K1: 256 q-octets x 8 (b,hh) groups; %8 pins (b,hh) to an XCD
    k_msamp<<<(L / 8) * 8, 256, 0, stream>>>(Q, K, idx, M);
    k_topk<<<B * H, 256, 0, stream>>>(M, top);
    k_scores<<<B * H * 16, 256, 0, stream>>>(Q, K, top, T, csum);
    k_tails<<<B * H, 64, 0, stream>>>(csum, tails, rden);
    k_ctx<<<B * H * JC, 256, 0, stream>>>(V, T, tails, part);
    k_red<<<(B * H * U * D + 255) / 256, 256, 0, stream>>>(part, rden, out);
}

// Round 11
// 149.646 us; speedup vs baseline: 2.5233x; 1.0026x over previous
//
#include <hip/hip_runtime.h>
#include <hip/hip_bf16.h>
#include <math.h>

#define B 4
#define L 2048
#define H 8
#define D 64
#define SK 40
#define U 40
#define JC 32          // j-chunks in k_ctx
#define JCL (L / JC)   // 64 j per chunk

// ws layout (bytes)
#define OFF_M     0                  // B*H*L floats = 262144 B
#define OFF_TOP   262144             // B*H*U ints  = 5120 B
#define OFF_T     270336             // B*H*U*L floats (E matrix) = 10485760 B
#define OFF_PART  10756096           // JC * B*H*U*D floats = 10485760 B
#define OFF_CSUM  21241856           // B*H*U*JC floats = 163840 B (end ~21.4 MB)

__device__ __forceinline__ float dot4(float4 a, float4 b) {
    return fmaf(a.x, b.x, fmaf(a.y, b.y, fmaf(a.z, b.z, a.w * b.w)));
}

// K1: M[b,h,q] = max_s dot(Q[bhq], K[bh,idx[q,s]]) - (1/L) * sum_s dot(...)
// FP32 ONLY: M feeds an ordering (top-k ranks index output rows); fp16 dot
// noise (~4e-3) exceeds adjacent-rank M gaps (~1e-3) and permutes rows
// (R9/R10 failed at absmax 2.25 from exactly this).
// XCD-locality: blockIdx%8 == b*2+hh pins each (b, h-half) to one XCD whose
// K working set is 2.1 MB < 4 MB L2. Wave = 2 queries; idx preloaded to regs
// and broadcast via shuffles for deep VMEM pipelining.
__global__ __launch_bounds__(256) void k_msamp(const float* __restrict__ Q,
                                               const float* __restrict__ K,
                                               const int* __restrict__ idx,
                                               float* __restrict__ M) {
    int g  = blockIdx.x & 7;        // = b*2 + hh  (XCD id under %8 round-robin)
    int b  = g >> 1;
    int hh = g & 1;
    int t  = threadIdx.x;
    int wave = t >> 6;
    int lane = t & 63;
    int qp = lane >> 5;             // 0/1: which query of this wave
    int hp = (lane >> 3) & 3;       // h' within half
    int c  = lane & 7;              // 8-float chunk of D
    int h  = hh * 4 + hp;
    int q  = (blockIdx.x >> 3) * 8 + wave * 2 + qp;

    const float* qrow = Q + (size_t)((b * L + q) * H + h) * D + c * 8;
    float4 qa = *(const float4*)qrow;
    float4 qb = *(const float4*)(qrow + 4);

    int s1 = lane & 31;
    int v1 = idx[q * SK + s1];
    int s2 = 32 + s1; if (s2 > SK - 1) s2 = SK - 1;   // clamp (dup, unused)
    int v2 = idx[q * SK + s2];

    const float* kbase = K + (size_t)b * L * H * D + (size_t)h * D + c * 8;

    float vmax = -__builtin_inff();
    float vsum = 0.f;
#pragma unroll 8
    for (int s = 0; s < SK; ++s) {
        int kidx = (s < 32) ? __shfl(v1, qp * 32 + s, 64)
                            : __shfl(v2, qp * 32 + (s - 32), 64);
        const float* kp = kbase + (size_t)kidx * (H * D);
        float4 ka = *(const float4*)kp;
        float4 kb = *(const float4*)(kp + 4);
        float d8 = dot4(qa, ka) + dot4(qb, kb);
        d8 += __shfl_xor(d8, 1, 64);
        d8 += __shfl_xor(d8, 2, 64);
        d8 += __shfl_xor(d8, 4, 64);
        vmax = fmaxf(vmax, d8);
        vsum += d8;
    }
    if (c == 0) M[(size_t)(b * H + h) * L + q] = vmax - vsum * (1.0f / (float)L);
}

// K2: top-U per (b,h): min-max-normalized 256-bin select + exact candidate
// ranking. Order: value descending, ties -> lowest index (== jax.lax.top_k).
__global__ __launch_bounds__(256) void k_topk(const float* __restrict__ M,
                                              int* __restrict__ top) {
    __shared__ unsigned long long cand[L];    // worst-case candidates, 16 KB
    __shared__ unsigned int bins[256];
    __shared__ unsigned int red[256];
    __shared__ int cnt2;

    int bh = blockIdx.x;
    int tid = threadIdx.x;
    const float* m = M + (size_t)bh * L;

    bins[tid] = 0;
    if (tid == 0) cnt2 = 0;

    const float4* m4 = (const float4*)(m + tid * 8);
    float4 fa = m4[0], fb = m4[1];
    float f8[8] = {fa.x, fa.y, fa.z, fa.w, fb.x, fb.y, fb.z, fb.w};
    unsigned int u8[8];
    unsigned int umin = 0xFFFFFFFFu, umax = 0u;
#pragma unroll
    for (int e = 0; e < 8; ++e) {
        unsigned int bits = __float_as_uint(f8[e]);
        unsigned int u = (bits & 0x80000000u) ? ~bits : (bits | 0x80000000u);
        u8[e] = u;
        umin = min(umin, u);
        umax = max(umax, u);
    }
    red[tid] = umin;
    __syncthreads();
    for (int s = 128; s; s >>= 1) {
        if (tid < s) red[tid] = min(red[tid], red[tid + s]);
        __syncthreads();
    }
    unsigned int kmin = red[0];
    __syncthreads();
    red[tid] = umax;
    __syncthreads();
    for (int s = 128; s; s >>= 1) {
        if (tid < s) red[tid] = max(red[tid], red[tid + s]);
        __syncthreads();
    }
    unsigned int kmax = red[0];
    __syncthreads();

    unsigned int range = kmax - kmin;
    if (range == 0u) {
        if (tid < U) top[bh * U + tid] = tid;
        return;
    }
    int hb = 31 - __clz(range);
    int shift = (hb > 7) ? (hb - 7) : 0;

#pragma unroll
    for (int e = 0; e < 8; ++e) {
        unsigned int bin = (u8[e] - kmin) >> shift;
        atomicAdd(&bins[bin], 1u);
    }
    __syncthreads();

    red[tid] = bins[tid];
    __syncthreads();
    for (int s = 1; s < 256; s <<= 1) {
        unsigned int add = (tid + s < 256) ? red[tid + s] : 0u;
        __syncthreads();
        red[tid] += add;
        __syncthreads();
    }
    int cnt = __syncthreads_count(red[tid] >= U);
    unsigned int t = (unsigned int)(cnt - 1);

#pragma unroll
    for (int e = 0; e < 8; ++e) {
        unsigned int u = u8[e];
        if (((u - kmin) >> shift) >= t) {
            int pos = atomicAdd(&cnt2, 1);
            int i = tid * 8 + e;
            cand[pos] = ((unsigned long long)u << 11) | (unsigned long long)(2047 - i);
        }
    }
    __syncthreads();
    int C = cnt2;

    for (int j = tid; j < C; j += 256) {
        unsigned long long kj = cand[j];
        int r = 0;
        for (int kk = 0; kk < C; ++kk) r += (cand[kk] > kj);
        if (r < U) top[bh * U + r] = 2047 - (int)(kj & 0x7FFull);
    }
}

// K3a (fp32): E[bh,u,k] = exp(0.125 * dot(Q[bh,top[u]], K[bh,k])) — no
// max-sub needed (|score| <~ 6, fp32-safe; softmax normalization in k_red).
// Also emits csum[bh][u][jc] = sum of E over each 64-col chunk.
__global__ __launch_bounds__(256) void k_scores(const float* __restrict__ Q,
                                                const float* __restrict__ K,
                                                const int* __restrict__ top,
                                                float* __restrict__ T,
                                                float* __restrict__ csum) {
    __shared__ float4 sQ4[U * 16];   // 40 rows x 64 floats = 10 KB
    int bh = blockIdx.x >> 4;        // 16 k-chunks of 128
    int kc = blockIdx.x & 15;
    int b = bh >> 3, h = bh & (H - 1);
    int tid = threadIdx.x;
    int lane = tid & 63;
    int w = tid >> 6;

    for (int i = tid; i < U * 16; i += 256) {
        int u = i >> 4, c = i & 15;
        int qidx = top[bh * U + u];
        sQ4[i] = *((const float4*)(Q + (size_t)((b * L + qidx) * H + h) * D) + c);
    }

    int k0 = kc * 128 + lane;
    const float4* kr0 = (const float4*)(K + (size_t)((b * L + k0) * H + h) * D);
    const float4* kr1 = (const float4*)(K + (size_t)((b * L + k0 + 64) * H + h) * D);
    float4 kv0[16], kv1[16];
#pragma unroll
    for (int i = 0; i < 16; ++i) { kv0[i] = kr0[i]; kv1[i] = kr1[i]; }
    __syncthreads();

    float* Tb = T + (size_t)bh * U * L;
    for (int uu = 0; uu < 10; ++uu) {
        int u = w * 10 + uu;
        float s0 = 0.f, s1 = 0.f;
#pragma unroll
        for (int i = 0; i < 16; ++i) {
            float4 q4 = sQ4[u * 16 + i];   // broadcast LDS read
            s0 += dot4(q4, kv0[i]);
            s1 += dot4(q4, kv1[i]);
        }
        float e0 = __expf(s0 * 0.125f);
        float e1 = __expf(s1 * 0.125f);
        Tb[(size_t)u * L + k0]      = e0;
        Tb[(size_t)u * L + k0 + 64] = e1;
        float c0 = e0, c1 = e1;
#pragma unroll
        for (int o = 1; o < 64; o <<= 1) {
            c0 += __shfl_xor(c0, o, 64);
            c1 += __shfl_xor(c1, o, 64);
        }
        if (lane == 0) {
            csum[((size_t)bh * U + u) * JC + 2 * kc]     = c0;
            csum[((size_t)bh * U + u) * JC + 2 * kc + 1] = c1;
        }
    }
}

// K3c: part[jc,bh,u,d] = sum_{j in chunk jc} Tsuf[u,j] * V[b,j,h,d] where
// Tsuf[u,j] = within-chunk inclusive suffix of E + tail (computed inline
// from csum: sum of chunks beyond jc).
__global__ __launch_bounds__(256) void k_ctx(const float* __restrict__ V,
                                             const float* __restrict__ E,
                                             const float* __restrict__ csum,
                                             float* __restrict__ part) {
    __shared__ float sT[U][JCL];            // 40 x 64 floats = 10 KB
    int bh = blockIdx.x >> 5;               // JC = 32 chunks
    int jc = blockIdx.x & 31;
    int b = bh >> 3, h = bh & (H - 1);
    int tid = threadIdx.x;
    int w = tid >> 6;                       // wave: u in [10w, 10w+10)
    int lane = tid & 63;
    int j2 = lane >> 4;                     // 0..3 j-subgroup
    int d4 = lane & 15;                     // float4 index along d
    int jlane = lane & 31;

    const float* Eg = E + (size_t)bh * U * L + jc * JCL;
#pragma unroll
    for (int r = 0; r < 10; ++r) {
        int u = w * 10 + r;
        // tail = sum of csum chunks beyond jc (both 32-lane halves compute it)
        float cv = csum[((size_t)bh * U + u) * JC + jlane];
        float tv = (jlane > jc) ? cv : 0.f;
        tv += __shfl_xor(tv, 1, 64);
        tv += __shfl_xor(tv, 2, 64);
        tv += __shfl_xor(tv, 4, 64);
        tv += __shfl_xor(tv, 8, 64);
        tv += __shfl_xor(tv, 16, 64);
        float v = Eg[(size_t)u * L + lane];
        // 6-step inclusive suffix scan across the wave
#pragma unroll
        for (int s = 1; s < 64; s <<= 1) {
            float o = __shfl_down(v, s, 64);
            v += (lane + s < 64) ? o : 0.f;
        }
        sT[u][lane] = v + tv;
    }
    __syncthreads();

    float4 acc[10];
#pragma unroll
    for (int uu = 0; uu < 10; ++uu) acc[uu] = make_float4(0.f, 0.f, 0.f, 0.f);

    const float* Vb = V + (size_t)(b * L) * (H * D) + (size_t)h * D + d4 * 4;
#pragma unroll 4
    for (int it = 0; it < JCL / 4; ++it) {
        int j = it * 4 + j2;
        float4 v4 = *(const float4*)(Vb + (size_t)(jc * JCL + j) * (H * D));
#pragma unroll
        for (int uu = 0; uu < 10; ++uu) {
            float tj = sT[w * 10 + uu][j];   // broadcast LDS read
            acc[uu].x = fmaf(tj, v4.x, acc[uu].x);
            acc[uu].y = fmaf(tj, v4.y, acc[uu].y);
            acc[uu].z = fmaf(tj, v4.z, acc[uu].z);
            acc[uu].w = fmaf(tj, v4.w, acc[uu].w);
        }
    }

    float* po = part + ((size_t)jc * (B * H) + bh) * (U * D);
#pragma unroll
    for (int uu = 0; uu < 10; ++uu) {
        float4 a = acc[uu];
        a.x += __shfl_xor(a.x, 16, 64); a.y += __shfl_xor(a.y, 16, 64);
        a.z += __shfl_xor(a.z, 16, 64); a.w += __shfl_xor(a.w, 16, 64);
        a.x += __shfl_xor(a.x, 32, 64); a.y += __shfl_xor(a.y, 32, 64);
        a.z += __shfl_xor(a.z, 32, 64); a.w += __shfl_xor(a.w, 32, 64);
        if (j2 == 0) *(float4*)(po + (w * 10 + uu) * D + d4 * 4) = a;
    }
}

// final reduce over the JC j-chunks + softmax normalization (denominator
// computed from csum inline; block covers 4 u-rows of one bh)
__global__ __launch_bounds__(256) void k_red(const float* __restrict__ part,
                                             const float* __restrict__ csum,
                                             float* __restrict__ out) {
    __shared__ float sden[4];
    int o = blockIdx.x * 256 + threadIdx.x;
    int bh = o / (U * D);
    int rest = o - bh * (U * D);
    int u = rest >> 6;
    int tid = threadIdx.x;
    int ubase = ((blockIdx.x * 256) % (U * D)) >> 6;

    if (tid < 128) {
        int ul = tid >> 5, j = tid & 31;
        float v = csum[((size_t)bh * U + ubase + ul) * JC + j];
        v += __shfl_xor(v, 1, 64);
        v += __shfl_xor(v, 2, 64);
        v += __shfl_xor(v, 4, 64);
        v += __shfl_xor(v, 8, 64);
        v += __shfl_xor(v, 16, 64);
        if (j == 0) sden[ul] = v;
    }
    __syncthreads();

    float s = 0.f;
#pragma unroll
    for (int jc = 0; jc < JC; ++jc)
        s += part[(size_t)(jc * (B * H) + bh) * (U * D) + rest];
    out[o] = s / sden[u - ubase];
}

extern "C" void kernel_launch(void* const* d_in, const int* in_sizes, int n_in,
                              void* d_out, int out_size, void* d_ws, size_t ws_size,
                              hipStream_t stream) {
    const float* Q  = (const float*)d_in[0];
    const float* K  = (const float*)d_in[1];
    const float* V  = (const float*)d_in[2];
    const int* idx  = (const int*)d_in[3];
    float* out = (float*)d_out;

    float* M    = (float*)((char*)d_ws + OFF_M);
    int*   top  = (int*)  ((char*)d_ws + OFF_TOP);
    float* T    = (float*)((char*)d_ws + OFF_T);
    float* part = (float*)((char*)d_ws + OFF_PART);
    float* csum = (float*)((char*)d_ws + OFF_CSUM);

    // 256 q-octets x 8 (b,hh) groups; %8 pins (b,hh) to an XCD
    k_msamp<<<(L / 8) * 8, 256, 0, stream>>>(Q, K, idx, M);
    k_topk<<<B * H, 256, 0, stream>>>(M, top);
    k_scores<<<B * H * 16, 256, 0, stream>>>(Q, K, top, T, csum);
    k_ctx<<<B * H * JC, 256, 0, stream>>>(V, T, csum, part);
    k_red<<<(B * H * U * D) / 256, 256, 0, stream>>>(part, csum, out);
}